// Round 1
// baseline (183.679 us; speedup 1.0000x reference)
//
#include <hip/hip_runtime.h>
#include <hip/hip_bf16.h>

// AdjustedNonLocalBlock: 3x conv1x1 -> attention(S=4096,D=64,B=4) -> conv1x1 + residual.
// fp32 I/O; bf16 internals for MFMA. 3-kernel pipeline.
// R9 theme: all three kernels were grid-starved (1-2 blocks/CU). Halve per-wave
// tiles to double resident waves; no extra HBM traffic.
//   1. qkv_fused: 32-n tiles, grid 128x4 (was 64x4) -> 2 blocks/CU
//   2. attn:      32 q-rows/wave, grid 32x4x8 (was 16x4x8) -> 4 blocks/CU
//   3. out_fused: 32-n tiles, grid 128x4 -> 2 blocks/CU

typedef unsigned int   u32;
typedef unsigned short u16;
typedef __attribute__((ext_vector_type(8))) short short8;   // 8x bf16 (MFMA A/B frag)
typedef __attribute__((ext_vector_type(4))) short short4v;  // 4x bf16 (LDS P store)
typedef __attribute__((ext_vector_type(4))) float f32x4;    // MFMA C/D frag

#define LOG2E 1.4426950408889634f
#define KSPLIT 8

__device__ __forceinline__ float b2f(u16 v) {
  union { u32 u; float f; } x; x.u = ((u32)v) << 16; return x.f;
}
__device__ __forceinline__ u16 f2b(float f) {
  u32 u = __float_as_uint(f);
  return (u16)((u + 0x8000u) >> 16);
}
// build a short8 bf16 frag from 8 consecutive fp32 (32B-aligned), with scale
__device__ __forceinline__ short8 load_w_frag(const float* p, float s) {
  const float4 f0 = ((const float4*)p)[0];
  const float4 f1 = ((const float4*)p)[1];
  union { u32 w[4]; short8 s8; } r;
  r.w[0] = (u32)f2b(f0.x * s) | ((u32)f2b(f0.y * s) << 16);
  r.w[1] = (u32)f2b(f0.z * s) | ((u32)f2b(f0.w * s) << 16);
  r.w[2] = (u32)f2b(f1.x * s) | ((u32)f2b(f1.y * s) << 16);
  r.w[3] = (u32)f2b(f1.z * s) | ((u32)f2b(f1.w * s) << 16);
  return r.s8;
}

// ---------------- workspace layout (bytes) ----------------
// Q    [4][4096][64]  bf16 @ 0     (2 MB)
// K    [4][4096][64]  bf16 @ 2 MB  (2 MB)
// Vt   [4][64][4096]  bf16 @ 4 MB  (2 MB)
// Opart[8][4][4096][64] bf16 @ 6 MB (16 MB)
// Lp   [8][4][4096] f32 @ 22 MB    (512 KB)  -> 22.5 MB

// grid (128 n-tiles of 32, 4 batches), block 256 = 4 waves.
// Stage x0,x1 [128c][32n] -> LDS xt[tensor][n][c] bf16; then per-wave MFMA convs.
// wave0: theta(x1)->Q, wave1: phi(x0)->K, wave2/3: g(x0)->Vt (o-halves).
__global__ __launch_bounds__(256) void qkv_fused_kernel(
    const float* __restrict__ x0, const float* __restrict__ x1,
    const float* __restrict__ tw, const float* __restrict__ tb,
    const float* __restrict__ pw, const float* __restrict__ pb,
    const float* __restrict__ gw, const float* __restrict__ gb,
    u16* __restrict__ Q, u16* __restrict__ K, u16* __restrict__ Vt)
{
  const int n0 = blockIdx.x * 32;
  const int b  = blockIdx.y;
  const int t  = threadIdx.x;

  __shared__ __align__(16) short xt[2][32][136];   // [tensor][n][c], +8 pad

  // staging: 8192 bf16 elements, idx = tensor*4096 + c*32 + n  (n fastest -> coalesced)
  #pragma unroll 8
  for (int i = 0; i < 32; ++i) {
    const int idx = i * 256 + t;
    const int tensor = idx >> 12;
    const int c = (idx >> 5) & 127;
    const int n = idx & 31;
    const float v = (tensor ? x1 : x0)[((size_t)b * 128 + c) * 4096 + n0 + n];
    xt[tensor][n][c] = (short)f2b(v);
  }
  asm volatile("" ::: "memory");
  __syncthreads();

  const int wave = t >> 6;
  const int lane = t & 63;
  const int quad = lane >> 4, l15 = lane & 15;

  if (wave < 2) {
    // Q (theta on x1) or K (phi on x0): C[n][o] = mfma(A=x[n][c], B=w[o][c])
    const int conv = wave;
    const float* wsrc = conv ? pw : tw;
    const float  ws   = conv ? 1.f : LOG2E;
    const short* xl   = &xt[conv ? 0 : 1][0][0];

    f32x4 acc[2][4];
    #pragma unroll
    for (int i = 0; i < 2; ++i)
      #pragma unroll
      for (int j = 0; j < 4; ++j) acc[i][j] = (f32x4){0.f, 0.f, 0.f, 0.f};

    #pragma unroll
    for (int kk = 0; kk < 4; ++kk) {
      short8 wf[4], xf[2];
      #pragma unroll
      for (int ot = 0; ot < 4; ++ot)
        wf[ot] = load_w_frag(wsrc + (ot * 16 + l15) * 128 + kk * 32 + quad * 8, ws);
      #pragma unroll
      for (int nt = 0; nt < 2; ++nt)
        xf[nt] = *(const short8*)(xl + (nt * 16 + l15) * 136 + kk * 32 + quad * 8);
      #pragma unroll
      for (int i = 0; i < 2; ++i)
        #pragma unroll
        for (int j = 0; j < 4; ++j)
          acc[i][j] = __builtin_amdgcn_mfma_f32_16x16x32_bf16(xf[i], wf[j], acc[i][j], 0, 0, 0);
    }

    u16* dst = (conv ? K : Q) + (size_t)b * 4096 * 64;
    const float* bias = conv ? pb : tb;
    const float bscale = conv ? 1.f : LOG2E;
    #pragma unroll
    for (int ot = 0; ot < 4; ++ot) {
      const float bv = bias[ot * 16 + l15] * bscale;
      #pragma unroll
      for (int nt = 0; nt < 2; ++nt)
        #pragma unroll
        for (int r = 0; r < 4; ++r) {
          const int n = n0 + nt * 16 + quad * 4 + r;
          dst[(size_t)n * 64 + ot * 16 + l15] = f2b(acc[nt][ot][r] + bv);
        }
    }
  } else {
    // Vt (g on x0): C[o][n] = mfma(A=w[o][c], B=x[n][c]); wave handles 32-o half
    const int oh = wave - 2;
    const short* xl = &xt[0][0][0];

    f32x4 acc[2][2];
    #pragma unroll
    for (int i = 0; i < 2; ++i)
      #pragma unroll
      for (int j = 0; j < 2; ++j) acc[i][j] = (f32x4){0.f, 0.f, 0.f, 0.f};

    #pragma unroll
    for (int kk = 0; kk < 4; ++kk) {
      short8 wf[2], xf[2];
      #pragma unroll
      for (int ot = 0; ot < 2; ++ot)
        wf[ot] = load_w_frag(gw + ((oh * 2 + ot) * 16 + l15) * 128 + kk * 32 + quad * 8, 1.f);
      #pragma unroll
      for (int nt = 0; nt < 2; ++nt)
        xf[nt] = *(const short8*)(xl + (nt * 16 + l15) * 136 + kk * 32 + quad * 8);
      #pragma unroll
      for (int i = 0; i < 2; ++i)
        #pragma unroll
        for (int j = 0; j < 2; ++j)
          acc[i][j] = __builtin_amdgcn_mfma_f32_16x16x32_bf16(wf[i], xf[j], acc[i][j], 0, 0, 0);
    }

    u16* dst = Vt + (size_t)b * 64 * 4096;
    #pragma unroll
    for (int ot = 0; ot < 2; ++ot)
      #pragma unroll
      for (int r = 0; r < 4; ++r) {
        const int o = (oh * 2 + ot) * 16 + quad * 4 + r;
        const float bv = gb[o];
        #pragma unroll
        for (int nc = 0; nc < 2; ++nc)
          dst[(size_t)o * 4096 + n0 + nc * 16 + l15] = f2b(acc[ot][nc][r] + bv);
      }
  }
}

// grid (32 q-tiles of 128, 4 batches, 8 ksplits), block 256 = 4 waves.
// Each wave owns 32 q-rows (was 64): 4096 waves total = 4 blocks/CU resident.
__global__ __launch_bounds__(256, 4) void attn_kernel(
    const u16* __restrict__ Q, const u16* __restrict__ K,
    const u16* __restrict__ Vt, u16* __restrict__ Opart,
    float* __restrict__ Lp)
{
  const int qt = blockIdx.x, b = blockIdx.y, ks = blockIdx.z;
  const int tid  = threadIdx.x;
  const int wave = tid >> 6;
  const int lane = tid & 63;
  const int quad = lane >> 4;
  const int l15  = lane & 15;

  __shared__ __align__(16) short P_lds[4][32][72];
  short* pw = &P_lds[wave][0][0];

  const int q0 = qt * 128 + wave * 32;
  const u16* Qb = Q  + (size_t)b * 4096 * 64;
  const u16* Kb = K  + (size_t)b * 4096 * 64;
  const u16* Vb = Vt + (size_t)b * 64 * 4096;

  short8 qf[2][2];
  #pragma unroll
  for (int nt = 0; nt < 2; ++nt) {
    const u16* qp = Qb + (size_t)(q0 + nt * 16 + l15) * 64 + quad * 8;
    qf[nt][0] = *(const short8*)qp;
    qf[nt][1] = *(const short8*)(qp + 32);
  }

  f32x4 oacc[2][4];
  #pragma unroll
  for (int i = 0; i < 2; ++i)
    #pragma unroll
    for (int j = 0; j < 4; ++j)
      oacc[i][j] = (f32x4){0.f, 0.f, 0.f, 0.f};
  float lsum[2] = {0.f, 0.f};

  const int kbase = ks * (4096 / KSPLIT);
  const int NKT   = 4096 / KSPLIT / 64;

  short8 kf[4][2];
  #pragma unroll
  for (int mt = 0; mt < 4; ++mt) {
    const u16* kp = Kb + (size_t)(kbase + mt * 16 + l15) * 64 + quad * 8;
    kf[mt][0] = *(const short8*)kp;
    kf[mt][1] = *(const short8*)(kp + 32);
  }

  for (int kt = 0; kt < NKT; ++kt) {
    const int k0 = kbase + kt * 64;

    short8 vf[4][2];
    #pragma unroll
    for (int nd = 0; nd < 4; ++nd) {
      const u16* vp = Vb + (size_t)(nd * 16 + l15) * 4096 + k0 + quad * 8;
      vf[nd][0] = *(const short8*)vp;
      vf[nd][1] = *(const short8*)(vp + 32);
    }

    #pragma unroll
    for (int mt = 0; mt < 4; ++mt) {
      #pragma unroll
      for (int nt = 0; nt < 2; ++nt) {
        f32x4 s = {0.f, 0.f, 0.f, 0.f};
        s = __builtin_amdgcn_mfma_f32_16x16x32_bf16(kf[mt][0], qf[nt][0], s, 0, 0, 0);
        s = __builtin_amdgcn_mfma_f32_16x16x32_bf16(kf[mt][1], qf[nt][1], s, 0, 0, 0);
        float p0 = exp2f(s[0]), p1 = exp2f(s[1]), p2 = exp2f(s[2]), p3 = exp2f(s[3]);
        lsum[nt] += (p0 + p1) + (p2 + p3);
        u32 u0 = __float_as_uint(p0) + 0x8000u;
        u32 u1 = __float_as_uint(p1) + 0x8000u;
        u32 u2 = __float_as_uint(p2) + 0x8000u;
        u32 u3 = __float_as_uint(p3) + 0x8000u;
        union { uint2 u; short4v s4; } pk;
        pk.u.x = __builtin_amdgcn_perm(u1, u0, 0x07060302u);
        pk.u.y = __builtin_amdgcn_perm(u3, u2, 0x07060302u);
        *(short4v*)(pw + (nt * 16 + l15) * 72 + mt * 16 + quad * 4) = pk.s4;
      }
    }

    if (kt < NKT - 1) {
      #pragma unroll
      for (int mt = 0; mt < 4; ++mt) {
        const u16* kp = Kb + (size_t)(k0 + 64 + mt * 16 + l15) * 64 + quad * 8;
        kf[mt][0] = *(const short8*)kp;
        kf[mt][1] = *(const short8*)(kp + 32);
      }
    }

    asm volatile("" ::: "memory");

    #pragma unroll
    for (int mq = 0; mq < 2; ++mq) {
      const short* pr = pw + (mq * 16 + l15) * 72 + quad * 8;
      short8 pa0 = *(const short8*)pr;
      short8 pa1 = *(const short8*)(pr + 32);
      #pragma unroll
      for (int nd = 0; nd < 4; ++nd) {
        oacc[mq][nd] = __builtin_amdgcn_mfma_f32_16x16x32_bf16(pa0, vf[nd][0], oacc[mq][nd], 0, 0, 0);
        oacc[mq][nd] = __builtin_amdgcn_mfma_f32_16x16x32_bf16(pa1, vf[nd][1], oacc[mq][nd], 0, 0, 0);
      }
    }

    asm volatile("" ::: "memory");
  }

  #pragma unroll
  for (int nt = 0; nt < 2; ++nt) {
    float v = lsum[nt];
    v += __shfl_xor(v, 16, 64);
    v += __shfl_xor(v, 32, 64);
    lsum[nt] = v;
  }
  float* LpB = Lp + ((size_t)ks * 4 + b) * 4096;
  if (quad == 0) {
    #pragma unroll
    for (int nt = 0; nt < 2; ++nt)
      LpB[q0 + nt * 16 + l15] = lsum[nt];
  }

  u16* Ob = Opart + ((size_t)ks * 4 + b) * 4096 * 64;
  #pragma unroll
  for (int mq = 0; mq < 2; ++mq)
    #pragma unroll
    for (int nd = 0; nd < 4; ++nd)
      #pragma unroll
      for (int r = 0; r < 4; ++r) {
        int q = q0 + mq * 16 + quad * 4 + r;
        Ob[(size_t)q * 64 + nd * 16 + l15] = f2b(oacc[mq][nd][r]);
      }
}

// grid (128 n-tiles of 32, 4 batches), block 256 = 4 waves.
// Phase 1: Y[n][64] = sum_ks(Opart)/sum_ks(Lp) -> LDS bf16. Phase 2: MFMA proj
// C[o][n] = mfma(A=W[o][ci], B=Y[n][ci]); out = C + Wb + x0.
__global__ __launch_bounds__(256) void out_fused_kernel(
    const u16* __restrict__ Opart, const float* __restrict__ Lp,
    const float* __restrict__ Wf, const float* __restrict__ Wbf,
    const float* __restrict__ x0, float* __restrict__ out)
{
  const int n0 = blockIdx.x * 32;
  const int b  = blockIdx.y;
  const int t  = threadIdx.x;

  __shared__ __align__(16) short Ys[32][72];   // [n][ci], +8 pad

  {
    const int nl = t >> 3;          // 0..31
    const int q8 = t & 7;           // 8-ch chunk
    const int ng = n0 + nl;

    float l = 0.f;
    #pragma unroll
    for (int ks = 0; ks < KSPLIT; ++ks)
      l += Lp[((size_t)ks * 4 + b) * 4096 + ng];

    float a[8];
    #pragma unroll
    for (int j = 0; j < 8; ++j) a[j] = 0.f;
    #pragma unroll
    for (int ks = 0; ks < KSPLIT; ++ks) {
      uint4 r = *(const uint4*)(Opart + (((size_t)ks * 4 + b) * 4096 + ng) * 64 + q8 * 8);
      u32 wds[4] = {r.x, r.y, r.z, r.w};
      #pragma unroll
      for (int j = 0; j < 4; ++j) {
        a[2 * j]     += __uint_as_float(wds[j] << 16);
        a[2 * j + 1] += __uint_as_float(wds[j] & 0xffff0000u);
      }
    }
    const float rinv = 1.f / l;
    union { u32 w[4]; short8 s8; } pk;
    #pragma unroll
    for (int j = 0; j < 4; ++j)
      pk.w[j] = (u32)f2b(a[2 * j] * rinv) | ((u32)f2b(a[2 * j + 1] * rinv) << 16);
    *(short8*)&Ys[nl][q8 * 8] = pk.s8;
  }
  asm volatile("" ::: "memory");
  __syncthreads();

  const int wave = t >> 6;
  const int lane = t & 63;
  const int quad = lane >> 4, l15 = lane & 15;

  f32x4 acc[2][2];   // [o-tile within wave][n-tile]
  #pragma unroll
  for (int i = 0; i < 2; ++i)
    #pragma unroll
    for (int j = 0; j < 2; ++j) acc[i][j] = (f32x4){0.f, 0.f, 0.f, 0.f};

  #pragma unroll
  for (int kk = 0; kk < 2; ++kk) {
    short8 wf[2], yf[2];
    #pragma unroll
    for (int ot = 0; ot < 2; ++ot)
      wf[ot] = load_w_frag(Wf + ((wave * 2 + ot) * 16 + l15) * 64 + kk * 32 + quad * 8, 1.f);
    #pragma unroll
    for (int nt = 0; nt < 2; ++nt)
      yf[nt] = *(const short8*)&Ys[nt * 16 + l15][kk * 32 + quad * 8];
    #pragma unroll
    for (int i = 0; i < 2; ++i)
      #pragma unroll
      for (int j = 0; j < 2; ++j)
        acc[i][j] = __builtin_amdgcn_mfma_f32_16x16x32_bf16(wf[i], yf[j], acc[i][j], 0, 0, 0);
  }

  #pragma unroll
  for (int ot = 0; ot < 2; ++ot)
    #pragma unroll
    for (int r = 0; r < 4; ++r) {
      const int o = (wave * 2 + ot) * 16 + quad * 4 + r;
      const float bv = Wbf[o];
      #pragma unroll
      for (int nt = 0; nt < 2; ++nt) {
        const size_t idx = ((size_t)(b * 128 + o)) * 4096 + n0 + nt * 16 + l15;
        out[idx] = acc[ot][nt][r] + bv + x0[idx];
      }
    }
}

extern "C" void kernel_launch(void* const* d_in, const int* in_sizes, int n_in,
                              void* d_out, int out_size, void* d_ws, size_t ws_size,
                              hipStream_t stream) {
  const float* x0 = (const float*)d_in[0];
  const float* x1 = (const float*)d_in[1];
  const float* gw = (const float*)d_in[2];
  const float* gb = (const float*)d_in[3];
  const float* tw = (const float*)d_in[4];
  const float* tb = (const float*)d_in[5];
  const float* pw = (const float*)d_in[6];
  const float* pb = (const float*)d_in[7];
  const float* Ww = (const float*)d_in[8];
  const float* Wb = (const float*)d_in[9];
  float* out = (float*)d_out;

  char* ws = (char*)d_ws;
  u16*   Qw    = (u16*)(ws + 0);
  u16*   Kw    = (u16*)(ws + (2u << 20));
  u16*   Vtw   = (u16*)(ws + (4u << 20));
  u16*   Opart = (u16*)(ws + (6u << 20));
  float* Lp    = (float*)(ws + (22u << 20));   // 22.5 MB total

  qkv_fused_kernel<<<dim3(128, 4), dim3(256), 0, stream>>>(
      x0, x1, tw, tb, pw, pb, gw, gb, Qw, Kw, Vtw);

  attn_kernel<<<dim3(32, 4, KSPLIT), dim3(256), 0, stream>>>(Qw, Kw, Vtw, Opart, Lp);

  out_fused_kernel<<<dim3(128, 4), dim3(256), 0, stream>>>(
      Opart, Lp, Ww, Wb, x0, out);
}

// Round 2
// 133.529 us; speedup vs baseline: 1.3756x; 1.3756x over previous
//
#include <hip/hip_runtime.h>
#include <hip/hip_bf16.h>

// AdjustedNonLocalBlock: 3x conv1x1 -> attention(S=4096,D=64,B=4) -> conv1x1 + residual.
// fp32 I/O; bf16 internals for MFMA. 3-kernel pipeline.
// R10: R8 structure (64 q-rows/wave) + cooperative K/V LDS staging (double-buffered,
// issue-early/write-late) to kill the 4x redundant per-wave K/V global loads that
// pinned attn at ~6.3 TB/s effective load BW. qkv staging vectorized to float4.

typedef unsigned int   u32;
typedef unsigned short u16;
typedef __attribute__((ext_vector_type(8))) short short8;   // 8x bf16 (MFMA A/B frag)
typedef __attribute__((ext_vector_type(4))) short short4v;  // 4x bf16 (LDS P store)
typedef __attribute__((ext_vector_type(4))) float f32x4;    // MFMA C/D frag

#define LOG2E 1.4426950408889634f
#define KSPLIT 8

__device__ __forceinline__ float b2f(u16 v) {
  union { u32 u; float f; } x; x.u = ((u32)v) << 16; return x.f;
}
__device__ __forceinline__ u16 f2b(float f) {
  u32 u = __float_as_uint(f);
  return (u16)((u + 0x8000u) >> 16);
}
// build a short8 bf16 frag from 8 consecutive fp32 (32B-aligned), with scale
__device__ __forceinline__ short8 load_w_frag(const float* p, float s) {
  const float4 f0 = ((const float4*)p)[0];
  const float4 f1 = ((const float4*)p)[1];
  union { u32 w[4]; short8 s8; } r;
  r.w[0] = (u32)f2b(f0.x * s) | ((u32)f2b(f0.y * s) << 16);
  r.w[1] = (u32)f2b(f0.z * s) | ((u32)f2b(f0.w * s) << 16);
  r.w[2] = (u32)f2b(f1.x * s) | ((u32)f2b(f1.y * s) << 16);
  r.w[3] = (u32)f2b(f1.z * s) | ((u32)f2b(f1.w * s) << 16);
  return r.s8;
}

// ---------------- workspace layout (bytes) ----------------
// Q    [4][4096][64]  bf16 @ 0     (2 MB)
// K    [4][4096][64]  bf16 @ 2 MB  (2 MB)
// Vt   [4][64][4096]  bf16 @ 4 MB  (2 MB)
// Opart[8][4][4096][64] bf16 @ 6 MB (16 MB)
// Lp   [8][4][4096] f32 @ 22 MB    (512 KB)  -> 22.5 MB

// grid (64 n-tiles of 64, 4 batches), block 256 = 4 waves.
// Stage x0,x1 [128c][64n] -> LDS xt[tensor][n][c] bf16; then per-wave MFMA convs.
// wave0: theta(x1)->Q, wave1: phi(x0)->K, wave2/3: g(x0)->Vt (o-halves).
__global__ __launch_bounds__(256) void qkv_fused_kernel(
    const float* __restrict__ x0, const float* __restrict__ x1,
    const float* __restrict__ tw, const float* __restrict__ tb,
    const float* __restrict__ pw, const float* __restrict__ pb,
    const float* __restrict__ gw, const float* __restrict__ gb,
    u16* __restrict__ Q, u16* __restrict__ K, u16* __restrict__ Vt)
{
  const int n0 = blockIdx.x * 64;
  const int b  = blockIdx.y;
  const int t  = threadIdx.x;

  __shared__ __align__(16) short xt[2][64][136];   // [tensor][n][c], +8 pad

  // staging: 16384 bf16 elements as 4096 float4 loads (16B/lane, coalesced).
  // idx = tensor*2048 + c*16 + n4  (n4 fastest -> consecutive 16B chunks)
  #pragma unroll
  for (int i = 0; i < 16; ++i) {
    const int idx = i * 256 + t;
    const int tensor = idx >> 11;
    const int c  = (idx >> 4) & 127;
    const int n4 = idx & 15;
    const float4 v = *(const float4*)(
        (tensor ? x1 : x0) + ((size_t)b * 128 + c) * 4096 + n0 + n4 * 4);
    short* d = &xt[tensor][n4 * 4][c];
    d[0]       = (short)f2b(v.x);
    d[136]     = (short)f2b(v.y);
    d[2 * 136] = (short)f2b(v.z);
    d[3 * 136] = (short)f2b(v.w);
  }
  asm volatile("" ::: "memory");
  __syncthreads();

  const int wave = t >> 6;
  const int lane = t & 63;
  const int quad = lane >> 4, l15 = lane & 15;

  if (wave < 2) {
    // Q (theta on x1) or K (phi on x0): C[n][o] = mfma(A=x[n][c], B=w[o][c])
    const int conv = wave;
    const float* wsrc = conv ? pw : tw;
    const float  ws   = conv ? 1.f : LOG2E;
    const short* xl   = &xt[conv ? 0 : 1][0][0];

    f32x4 acc[4][4];
    #pragma unroll
    for (int i = 0; i < 4; ++i)
      #pragma unroll
      for (int j = 0; j < 4; ++j) acc[i][j] = (f32x4){0.f, 0.f, 0.f, 0.f};

    #pragma unroll
    for (int kk = 0; kk < 4; ++kk) {
      short8 wf[4], xf[4];
      #pragma unroll
      for (int ot = 0; ot < 4; ++ot)
        wf[ot] = load_w_frag(wsrc + (ot * 16 + l15) * 128 + kk * 32 + quad * 8, ws);
      #pragma unroll
      for (int nt = 0; nt < 4; ++nt)
        xf[nt] = *(const short8*)(xl + (nt * 16 + l15) * 136 + kk * 32 + quad * 8);
      #pragma unroll
      for (int i = 0; i < 4; ++i)
        #pragma unroll
        for (int j = 0; j < 4; ++j)
          acc[i][j] = __builtin_amdgcn_mfma_f32_16x16x32_bf16(xf[i], wf[j], acc[i][j], 0, 0, 0);
    }

    u16* dst = (conv ? K : Q) + (size_t)b * 4096 * 64;
    const float* bias = conv ? pb : tb;
    const float bscale = conv ? 1.f : LOG2E;
    #pragma unroll
    for (int ot = 0; ot < 4; ++ot) {
      const float bv = bias[ot * 16 + l15] * bscale;
      #pragma unroll
      for (int nt = 0; nt < 4; ++nt)
        #pragma unroll
        for (int r = 0; r < 4; ++r) {
          const int n = n0 + nt * 16 + quad * 4 + r;
          dst[(size_t)n * 64 + ot * 16 + l15] = f2b(acc[nt][ot][r] + bv);
        }
    }
  } else {
    // Vt (g on x0): C[o][n] = mfma(A=w[o][c], B=x[n][c]); wave handles 32-o half
    const int oh = wave - 2;
    const short* xl = &xt[0][0][0];

    f32x4 acc[2][4];
    #pragma unroll
    for (int i = 0; i < 2; ++i)
      #pragma unroll
      for (int j = 0; j < 4; ++j) acc[i][j] = (f32x4){0.f, 0.f, 0.f, 0.f};

    #pragma unroll
    for (int kk = 0; kk < 4; ++kk) {
      short8 wf[2], xf[4];
      #pragma unroll
      for (int ot = 0; ot < 2; ++ot)
        wf[ot] = load_w_frag(gw + ((oh * 2 + ot) * 16 + l15) * 128 + kk * 32 + quad * 8, 1.f);
      #pragma unroll
      for (int nt = 0; nt < 4; ++nt)
        xf[nt] = *(const short8*)(xl + (nt * 16 + l15) * 136 + kk * 32 + quad * 8);
      #pragma unroll
      for (int i = 0; i < 2; ++i)
        #pragma unroll
        for (int j = 0; j < 4; ++j)
          acc[i][j] = __builtin_amdgcn_mfma_f32_16x16x32_bf16(wf[i], xf[j], acc[i][j], 0, 0, 0);
    }

    u16* dst = Vt + (size_t)b * 64 * 4096;
    #pragma unroll
    for (int ot = 0; ot < 2; ++ot)
      #pragma unroll
      for (int r = 0; r < 4; ++r) {
        const int o = (oh * 2 + ot) * 16 + quad * 4 + r;
        const float bv = gb[o];
        #pragma unroll
        for (int nc = 0; nc < 4; ++nc)
          dst[(size_t)o * 4096 + n0 + nc * 16 + l15] = f2b(acc[ot][nc][r] + bv);
      }
  }
}

// grid (16 q-tiles of 256, 4 batches, 8 ksplits), block 256 = 4 waves.
// R10: K/V tiles staged cooperatively into LDS once per block (was: each of the
// 4 waves loaded identical K/V from global -> 4x redundant traffic). Double
// buffer, loads issued before compute, LDS write after barrier (T14).
__global__ __launch_bounds__(256) void attn_kernel(
    const u16* __restrict__ Q, const u16* __restrict__ K,
    const u16* __restrict__ Vt, u16* __restrict__ Opart,
    float* __restrict__ Lp)
{
  const int qt = blockIdx.x, b = blockIdx.y, ks = blockIdx.z;
  const int tid  = threadIdx.x;
  const int wave = tid >> 6;
  const int lane = tid & 63;
  const int quad = lane >> 4;
  const int l15  = lane & 15;

  __shared__ __align__(16) short K_lds[2][64][72];   // [buf][k-row][ch], +8 pad
  __shared__ __align__(16) short V_lds[2][64][72];   // [buf][ch][k-col], +8 pad
  __shared__ __align__(16) short P_lds[4][64][72];   // per-wave P tile
  short* pw = &P_lds[wave][0][0];

  const int q0 = qt * 256 + wave * 64;
  const u16* Qb = Q  + (size_t)b * 4096 * 64;
  const u16* Kb = K  + (size_t)b * 4096 * 64;
  const u16* Vb = Vt + (size_t)b * 64 * 4096;

  const int kbase = ks * (4096 / KSPLIT);
  const int NKT   = 4096 / KSPLIT / 64;

  // cooperative staging coords: thread covers rows r0 and r0+32, 16B chunk c0
  const int r0 = tid >> 3;   // 0..31
  const int c0 = tid & 7;    // 0..7 (x8 shorts = 16B)

  short8 qf[4][2];
  #pragma unroll
  for (int nt = 0; nt < 4; ++nt) {
    const u16* qp = Qb + (size_t)(q0 + nt * 16 + l15) * 64 + quad * 8;
    qf[nt][0] = *(const short8*)qp;
    qf[nt][1] = *(const short8*)(qp + 32);
  }

  f32x4 oacc[4][4];
  #pragma unroll
  for (int i = 0; i < 4; ++i)
    #pragma unroll
    for (int j = 0; j < 4; ++j)
      oacc[i][j] = (f32x4){0.f, 0.f, 0.f, 0.f};
  float lsum[4] = {0.f, 0.f, 0.f, 0.f};

  // prolog: stage tile 0 into buf 0
  {
    const u16* kg = Kb + (size_t)kbase * 64;
    uint4 ka0 = *(const uint4*)(kg + (size_t)r0 * 64 + c0 * 8);
    uint4 ka1 = *(const uint4*)(kg + (size_t)(r0 + 32) * 64 + c0 * 8);
    uint4 va0 = *(const uint4*)(Vb + (size_t)r0 * 4096 + kbase + c0 * 8);
    uint4 va1 = *(const uint4*)(Vb + (size_t)(r0 + 32) * 4096 + kbase + c0 * 8);
    *(uint4*)&K_lds[0][r0][c0 * 8]      = ka0;
    *(uint4*)&K_lds[0][r0 + 32][c0 * 8] = ka1;
    *(uint4*)&V_lds[0][r0][c0 * 8]      = va0;
    *(uint4*)&V_lds[0][r0 + 32][c0 * 8] = va1;
  }
  __syncthreads();

  for (int kt = 0; kt < NKT; ++kt) {
    const int buf = kt & 1;
    const bool pre = (kt + 1 < NKT);

    // issue next tile's global loads early (latency hides under MFMA+exp2)
    uint4 ka0, ka1, va0, va1;
    if (pre) {
      const int k1 = kbase + (kt + 1) * 64;
      const u16* kg = Kb + (size_t)k1 * 64;
      ka0 = *(const uint4*)(kg + (size_t)r0 * 64 + c0 * 8);
      ka1 = *(const uint4*)(kg + (size_t)(r0 + 32) * 64 + c0 * 8);
      va0 = *(const uint4*)(Vb + (size_t)r0 * 4096 + k1 + c0 * 8);
      va1 = *(const uint4*)(Vb + (size_t)(r0 + 32) * 4096 + k1 + c0 * 8);
    }

    // K frags from LDS
    short8 kf[4][2];
    #pragma unroll
    for (int mt = 0; mt < 4; ++mt) {
      kf[mt][0] = *(const short8*)&K_lds[buf][mt * 16 + l15][quad * 8];
      kf[mt][1] = *(const short8*)&K_lds[buf][mt * 16 + l15][quad * 8 + 32];
    }

    #pragma unroll
    for (int mt = 0; mt < 4; ++mt) {
      #pragma unroll
      for (int nt = 0; nt < 4; ++nt) {
        f32x4 s = {0.f, 0.f, 0.f, 0.f};
        s = __builtin_amdgcn_mfma_f32_16x16x32_bf16(kf[mt][0], qf[nt][0], s, 0, 0, 0);
        s = __builtin_amdgcn_mfma_f32_16x16x32_bf16(kf[mt][1], qf[nt][1], s, 0, 0, 0);
        float p0 = exp2f(s[0]), p1 = exp2f(s[1]), p2 = exp2f(s[2]), p3 = exp2f(s[3]);
        lsum[nt] += (p0 + p1) + (p2 + p3);
        u32 u0 = __float_as_uint(p0) + 0x8000u;
        u32 u1 = __float_as_uint(p1) + 0x8000u;
        u32 u2 = __float_as_uint(p2) + 0x8000u;
        u32 u3 = __float_as_uint(p3) + 0x8000u;
        union { uint2 u; short4v s4; } pk;
        pk.u.x = __builtin_amdgcn_perm(u1, u0, 0x07060302u);
        pk.u.y = __builtin_amdgcn_perm(u3, u2, 0x07060302u);
        *(short4v*)(pw + (nt * 16 + l15) * 72 + mt * 16 + quad * 4) = pk.s4;
      }
    }

    asm volatile("" ::: "memory");

    // V frags from LDS
    short8 vf[4][2];
    #pragma unroll
    for (int nd = 0; nd < 4; ++nd) {
      vf[nd][0] = *(const short8*)&V_lds[buf][nd * 16 + l15][quad * 8];
      vf[nd][1] = *(const short8*)&V_lds[buf][nd * 16 + l15][quad * 8 + 32];
    }

    #pragma unroll
    for (int mq = 0; mq < 4; ++mq) {
      const short* pr = pw + (mq * 16 + l15) * 72 + quad * 8;
      short8 pa0 = *(const short8*)pr;
      short8 pa1 = *(const short8*)(pr + 32);
      #pragma unroll
      for (int nd = 0; nd < 4; ++nd) {
        oacc[mq][nd] = __builtin_amdgcn_mfma_f32_16x16x32_bf16(pa0, vf[nd][0], oacc[mq][nd], 0, 0, 0);
        oacc[mq][nd] = __builtin_amdgcn_mfma_f32_16x16x32_bf16(pa1, vf[nd][1], oacc[mq][nd], 0, 0, 0);
      }
    }

    asm volatile("" ::: "memory");

    __syncthreads();   // all waves done reading buf (and done with prev writes)
    if (pre) {
      const int nb = buf ^ 1;
      *(uint4*)&K_lds[nb][r0][c0 * 8]      = ka0;
      *(uint4*)&K_lds[nb][r0 + 32][c0 * 8] = ka1;
      *(uint4*)&V_lds[nb][r0][c0 * 8]      = va0;
      *(uint4*)&V_lds[nb][r0 + 32][c0 * 8] = va1;
      __syncthreads();
    }
  }

  #pragma unroll
  for (int nt = 0; nt < 4; ++nt) {
    float v = lsum[nt];
    v += __shfl_xor(v, 16, 64);
    v += __shfl_xor(v, 32, 64);
    lsum[nt] = v;
  }
  float* LpB = Lp + ((size_t)ks * 4 + b) * 4096;
  if (quad == 0) {
    #pragma unroll
    for (int nt = 0; nt < 4; ++nt)
      LpB[q0 + nt * 16 + l15] = lsum[nt];
  }

  u16* Ob = Opart + ((size_t)ks * 4 + b) * 4096 * 64;
  #pragma unroll
  for (int mq = 0; mq < 4; ++mq)
    #pragma unroll
    for (int nd = 0; nd < 4; ++nd)
      #pragma unroll
      for (int r = 0; r < 4; ++r) {
        int q = q0 + mq * 16 + quad * 4 + r;
        Ob[(size_t)q * 64 + nd * 16 + l15] = f2b(oacc[mq][nd][r]);
      }
}

// grid (64 n-tiles of 64, 4 batches), block 256 = 4 waves.
// Phase 1: Y[n][64] = sum_ks(Opart)/sum_ks(Lp) -> LDS bf16. Phase 2: MFMA proj
// C[o][n] = mfma(A=W[o][ci], B=Y[n][ci]); out = C + Wb + x0.
__global__ __launch_bounds__(256) void out_fused_kernel(
    const u16* __restrict__ Opart, const float* __restrict__ Lp,
    const float* __restrict__ Wf, const float* __restrict__ Wbf,
    const float* __restrict__ x0, float* __restrict__ out)
{
  const int n0 = blockIdx.x * 64;
  const int b  = blockIdx.y;
  const int t  = threadIdx.x;

  __shared__ __align__(16) short Ys[64][72];   // [n][ci], +8 pad

  {
    const int nl = t >> 2;          // 0..63
    const int q4 = t & 3;           // 16-ch chunk
    const int ng = n0 + nl;

    float l = 0.f;
    #pragma unroll
    for (int ks = 0; ks < KSPLIT; ++ks)
      l += Lp[((size_t)ks * 4 + b) * 4096 + ng];

    float a[16];
    #pragma unroll
    for (int j = 0; j < 16; ++j) a[j] = 0.f;
    #pragma unroll
    for (int ks = 0; ks < KSPLIT; ++ks) {
      const uint4* row = (const uint4*)(Opart + (((size_t)ks * 4 + b) * 4096 + ng) * 64 + q4 * 16);
      #pragma unroll
      for (int v = 0; v < 2; ++v) {
        uint4 r = row[v];
        u32 wds[4] = {r.x, r.y, r.z, r.w};
        #pragma unroll
        for (int j = 0; j < 4; ++j) {
          a[v * 8 + 2 * j]     += __uint_as_float(wds[j] << 16);
          a[v * 8 + 2 * j + 1] += __uint_as_float(wds[j] & 0xffff0000u);
        }
      }
    }
    const float rinv = 1.f / l;
    union { u32 w[8]; short8 s8[2]; } pk;
    #pragma unroll
    for (int j = 0; j < 8; ++j)
      pk.w[j] = (u32)f2b(a[2 * j] * rinv) | ((u32)f2b(a[2 * j + 1] * rinv) << 16);
    *(short8*)&Ys[nl][q4 * 16]     = pk.s8[0];
    *(short8*)&Ys[nl][q4 * 16 + 8] = pk.s8[1];
  }
  asm volatile("" ::: "memory");
  __syncthreads();

  const int wave = t >> 6;
  const int lane = t & 63;
  const int quad = lane >> 4, l15 = lane & 15;

  f32x4 acc[2][4];   // [o-tile within wave][n-tile]
  #pragma unroll
  for (int i = 0; i < 2; ++i)
    #pragma unroll
    for (int j = 0; j < 4; ++j) acc[i][j] = (f32x4){0.f, 0.f, 0.f, 0.f};

  #pragma unroll
  for (int kk = 0; kk < 2; ++kk) {
    short8 wf[2], yf[4];
    #pragma unroll
    for (int ot = 0; ot < 2; ++ot)
      wf[ot] = load_w_frag(Wf + ((wave * 2 + ot) * 16 + l15) * 64 + kk * 32 + quad * 8, 1.f);
    #pragma unroll
    for (int nt = 0; nt < 4; ++nt)
      yf[nt] = *(const short8*)&Ys[nt * 16 + l15][kk * 32 + quad * 8];
    #pragma unroll
    for (int i = 0; i < 2; ++i)
      #pragma unroll
      for (int j = 0; j < 4; ++j)
        acc[i][j] = __builtin_amdgcn_mfma_f32_16x16x32_bf16(wf[i], yf[j], acc[i][j], 0, 0, 0);
  }

  #pragma unroll
  for (int ot = 0; ot < 2; ++ot)
    #pragma unroll
    for (int r = 0; r < 4; ++r) {
      const int o = (wave * 2 + ot) * 16 + quad * 4 + r;
      const float bv = Wbf[o];
      #pragma unroll
      for (int nt = 0; nt < 4; ++nt) {
        const size_t idx = ((size_t)(b * 128 + o)) * 4096 + n0 + nt * 16 + l15;
        out[idx] = acc[ot][nt][r] + bv + x0[idx];
      }
    }
}

extern "C" void kernel_launch(void* const* d_in, const int* in_sizes, int n_in,
                              void* d_out, int out_size, void* d_ws, size_t ws_size,
                              hipStream_t stream) {
  const float* x0 = (const float*)d_in[0];
  const float* x1 = (const float*)d_in[1];
  const float* gw = (const float*)d_in[2];
  const float* gb = (const float*)d_in[3];
  const float* tw = (const float*)d_in[4];
  const float* tb = (const float*)d_in[5];
  const float* pw = (const float*)d_in[6];
  const float* pb = (const float*)d_in[7];
  const float* Ww = (const float*)d_in[8];
  const float* Wb = (const float*)d_in[9];
  float* out = (float*)d_out;

  char* ws = (char*)d_ws;
  u16*   Qw    = (u16*)(ws + 0);
  u16*   Kw    = (u16*)(ws + (2u << 20));
  u16*   Vtw   = (u16*)(ws + (4u << 20));
  u16*   Opart = (u16*)(ws + (6u << 20));
  float* Lp    = (float*)(ws + (22u << 20));   // 22.5 MB total

  qkv_fused_kernel<<<dim3(64, 4), dim3(256), 0, stream>>>(
      x0, x1, tw, tb, pw, pb, gw, gb, Qw, Kw, Vtw);

  attn_kernel<<<dim3(16, 4, KSPLIT), dim3(256), 0, stream>>>(Qw, Kw, Vtw, Opart, Lp);

  out_fused_kernel<<<dim3(64, 4), dim3(256), 0, stream>>>(
      Opart, Lp, Ww, Wb, x0, out);
}

// Round 3
// 126.969 us; speedup vs baseline: 1.4466x; 1.0517x over previous
//
#include <hip/hip_runtime.h>
#include <hip/hip_bf16.h>

// AdjustedNonLocalBlock: 3x conv1x1 -> attention(S=4096,D=64,B=4) -> conv1x1 + residual.
// fp32 I/O; bf16 internals for MFMA. 3-kernel pipeline.
// R11: attn was latency/barrier-bound at 2 waves/SIMD. Shrink LDS 73.7->28.7 KB
// (32 q-rows/wave, halved P tile with immediate PV per 32-k half, single-buffered
// K/V with reg prefetch) -> grid 1024 blocks at 4 blocks/CU = 4 waves/SIMD.
// Traffic ~unchanged (K/V re-reads L2-resident). qkv/out unchanged from R10.

typedef unsigned int   u32;
typedef unsigned short u16;
typedef __attribute__((ext_vector_type(8))) short short8;   // 8x bf16 (MFMA A/B frag)
typedef __attribute__((ext_vector_type(4))) short short4v;  // 4x bf16 (LDS P store)
typedef __attribute__((ext_vector_type(4))) float f32x4;    // MFMA C/D frag

#define LOG2E 1.4426950408889634f
#define KSPLIT 8

__device__ __forceinline__ float b2f(u16 v) {
  union { u32 u; float f; } x; x.u = ((u32)v) << 16; return x.f;
}
__device__ __forceinline__ u16 f2b(float f) {
  u32 u = __float_as_uint(f);
  return (u16)((u + 0x8000u) >> 16);
}
// build a short8 bf16 frag from 8 consecutive fp32 (32B-aligned), with scale
__device__ __forceinline__ short8 load_w_frag(const float* p, float s) {
  const float4 f0 = ((const float4*)p)[0];
  const float4 f1 = ((const float4*)p)[1];
  union { u32 w[4]; short8 s8; } r;
  r.w[0] = (u32)f2b(f0.x * s) | ((u32)f2b(f0.y * s) << 16);
  r.w[1] = (u32)f2b(f0.z * s) | ((u32)f2b(f0.w * s) << 16);
  r.w[2] = (u32)f2b(f1.x * s) | ((u32)f2b(f1.y * s) << 16);
  r.w[3] = (u32)f2b(f1.z * s) | ((u32)f2b(f1.w * s) << 16);
  return r.s8;
}

// ---------------- workspace layout (bytes) ----------------
// Q    [4][4096][64]  bf16 @ 0     (2 MB)
// K    [4][4096][64]  bf16 @ 2 MB  (2 MB)
// Vt   [4][64][4096]  bf16 @ 4 MB  (2 MB)
// Opart[8][4][4096][64] bf16 @ 6 MB (16 MB)
// Lp   [8][4][4096] f32 @ 22 MB    (512 KB)  -> 22.5 MB

// grid (64 n-tiles of 64, 4 batches), block 256 = 4 waves.
// Stage x0,x1 [128c][64n] -> LDS xt[tensor][n][c] bf16; then per-wave MFMA convs.
// wave0: theta(x1)->Q, wave1: phi(x0)->K, wave2/3: g(x0)->Vt (o-halves).
__global__ __launch_bounds__(256) void qkv_fused_kernel(
    const float* __restrict__ x0, const float* __restrict__ x1,
    const float* __restrict__ tw, const float* __restrict__ tb,
    const float* __restrict__ pw, const float* __restrict__ pb,
    const float* __restrict__ gw, const float* __restrict__ gb,
    u16* __restrict__ Q, u16* __restrict__ K, u16* __restrict__ Vt)
{
  const int n0 = blockIdx.x * 64;
  const int b  = blockIdx.y;
  const int t  = threadIdx.x;

  __shared__ __align__(16) short xt[2][64][136];   // [tensor][n][c], +8 pad

  // staging: 16384 bf16 elements as 4096 float4 loads (16B/lane, coalesced).
  // idx = tensor*2048 + c*16 + n4  (n4 fastest -> consecutive 16B chunks)
  #pragma unroll
  for (int i = 0; i < 16; ++i) {
    const int idx = i * 256 + t;
    const int tensor = idx >> 11;
    const int c  = (idx >> 4) & 127;
    const int n4 = idx & 15;
    const float4 v = *(const float4*)(
        (tensor ? x1 : x0) + ((size_t)b * 128 + c) * 4096 + n0 + n4 * 4);
    short* d = &xt[tensor][n4 * 4][c];
    d[0]       = (short)f2b(v.x);
    d[136]     = (short)f2b(v.y);
    d[2 * 136] = (short)f2b(v.z);
    d[3 * 136] = (short)f2b(v.w);
  }
  asm volatile("" ::: "memory");
  __syncthreads();

  const int wave = t >> 6;
  const int lane = t & 63;
  const int quad = lane >> 4, l15 = lane & 15;

  if (wave < 2) {
    // Q (theta on x1) or K (phi on x0): C[n][o] = mfma(A=x[n][c], B=w[o][c])
    const int conv = wave;
    const float* wsrc = conv ? pw : tw;
    const float  ws   = conv ? 1.f : LOG2E;
    const short* xl   = &xt[conv ? 0 : 1][0][0];

    f32x4 acc[4][4];
    #pragma unroll
    for (int i = 0; i < 4; ++i)
      #pragma unroll
      for (int j = 0; j < 4; ++j) acc[i][j] = (f32x4){0.f, 0.f, 0.f, 0.f};

    #pragma unroll
    for (int kk = 0; kk < 4; ++kk) {
      short8 wf[4], xf[4];
      #pragma unroll
      for (int ot = 0; ot < 4; ++ot)
        wf[ot] = load_w_frag(wsrc + (ot * 16 + l15) * 128 + kk * 32 + quad * 8, ws);
      #pragma unroll
      for (int nt = 0; nt < 4; ++nt)
        xf[nt] = *(const short8*)(xl + (nt * 16 + l15) * 136 + kk * 32 + quad * 8);
      #pragma unroll
      for (int i = 0; i < 4; ++i)
        #pragma unroll
        for (int j = 0; j < 4; ++j)
          acc[i][j] = __builtin_amdgcn_mfma_f32_16x16x32_bf16(xf[i], wf[j], acc[i][j], 0, 0, 0);
    }

    u16* dst = (conv ? K : Q) + (size_t)b * 4096 * 64;
    const float* bias = conv ? pb : tb;
    const float bscale = conv ? 1.f : LOG2E;
    #pragma unroll
    for (int ot = 0; ot < 4; ++ot) {
      const float bv = bias[ot * 16 + l15] * bscale;
      #pragma unroll
      for (int nt = 0; nt < 4; ++nt)
        #pragma unroll
        for (int r = 0; r < 4; ++r) {
          const int n = n0 + nt * 16 + quad * 4 + r;
          dst[(size_t)n * 64 + ot * 16 + l15] = f2b(acc[nt][ot][r] + bv);
        }
    }
  } else {
    // Vt (g on x0): C[o][n] = mfma(A=w[o][c], B=x[n][c]); wave handles 32-o half
    const int oh = wave - 2;
    const short* xl = &xt[0][0][0];

    f32x4 acc[2][4];
    #pragma unroll
    for (int i = 0; i < 2; ++i)
      #pragma unroll
      for (int j = 0; j < 4; ++j) acc[i][j] = (f32x4){0.f, 0.f, 0.f, 0.f};

    #pragma unroll
    for (int kk = 0; kk < 4; ++kk) {
      short8 wf[2], xf[4];
      #pragma unroll
      for (int ot = 0; ot < 2; ++ot)
        wf[ot] = load_w_frag(gw + ((oh * 2 + ot) * 16 + l15) * 128 + kk * 32 + quad * 8, 1.f);
      #pragma unroll
      for (int nt = 0; nt < 4; ++nt)
        xf[nt] = *(const short8*)(xl + (nt * 16 + l15) * 136 + kk * 32 + quad * 8);
      #pragma unroll
      for (int i = 0; i < 2; ++i)
        #pragma unroll
        for (int j = 0; j < 4; ++j)
          acc[i][j] = __builtin_amdgcn_mfma_f32_16x16x32_bf16(wf[i], xf[j], acc[i][j], 0, 0, 0);
    }

    u16* dst = Vt + (size_t)b * 64 * 4096;
    #pragma unroll
    for (int ot = 0; ot < 2; ++ot)
      #pragma unroll
      for (int r = 0; r < 4; ++r) {
        const int o = (oh * 2 + ot) * 16 + quad * 4 + r;
        const float bv = gb[o];
        #pragma unroll
        for (int nc = 0; nc < 4; ++nc)
          dst[(size_t)o * 4096 + n0 + nc * 16 + l15] = f2b(acc[ot][nc][r] + bv);
      }
  }
}

// grid (32 q-tiles of 128, 4 batches, 8 ksplits) = 1024 blocks, block 256 = 4 waves.
// Each wave owns 32 q-rows. LDS = K/V single-buffer (18.4 KB) + halved P tile
// (4 x 32x40 = 10.2 KB) = 28.7 KB -> 4 blocks/CU resident (4 waves/SIMD).
// Per 64-k tile: two 32-k phases, each {QK MFMA -> exp2/pack -> P-half -> PV MFMA}.
__global__ __launch_bounds__(256, 4) void attn_kernel(
    const u16* __restrict__ Q, const u16* __restrict__ K,
    const u16* __restrict__ Vt, u16* __restrict__ Opart,
    float* __restrict__ Lp)
{
  const int qt = blockIdx.x, b = blockIdx.y, ks = blockIdx.z;
  const int tid  = threadIdx.x;
  const int wave = tid >> 6;
  const int lane = tid & 63;
  const int quad = lane >> 4;
  const int l15  = lane & 15;

  __shared__ __align__(16) short K_lds[64][72];     // [k-row][ch], +8 pad
  __shared__ __align__(16) short V_lds[64][72];     // [ch][k-col], +8 pad
  __shared__ __align__(16) short P_lds[4][32][40];  // per-wave P half-tile (32q x 32k, +8)
  short* pw = &P_lds[wave][0][0];

  const int q0 = qt * 128 + wave * 32;
  const u16* Qb = Q  + (size_t)b * 4096 * 64;
  const u16* Kb = K  + (size_t)b * 4096 * 64;
  const u16* Vb = Vt + (size_t)b * 64 * 4096;

  const int kbase = ks * (4096 / KSPLIT);
  const int NKT   = 4096 / KSPLIT / 64;

  // cooperative staging coords: 256 threads cover 64 rows x 2 16B-chunks each
  const int sr = tid >> 2;        // 0..63
  const int sc = (tid & 3) * 8;   // 0,8,16,24 (shorts)

  short8 qf[2][2];
  #pragma unroll
  for (int nt = 0; nt < 2; ++nt) {
    const u16* qp = Qb + (size_t)(q0 + nt * 16 + l15) * 64 + quad * 8;
    qf[nt][0] = *(const short8*)qp;
    qf[nt][1] = *(const short8*)(qp + 32);
  }

  f32x4 oacc[2][4];
  #pragma unroll
  for (int i = 0; i < 2; ++i)
    #pragma unroll
    for (int j = 0; j < 4; ++j)
      oacc[i][j] = (f32x4){0.f, 0.f, 0.f, 0.f};
  float lsum[2] = {0.f, 0.f};

  // prolog: stage tile 0
  {
    const u16* kg = Kb + (size_t)kbase * 64;
    uint4 ka = *(const uint4*)(kg + (size_t)sr * 64 + sc);
    uint4 kb = *(const uint4*)(kg + (size_t)sr * 64 + sc + 32);
    uint4 va = *(const uint4*)(Vb + (size_t)sr * 4096 + kbase + sc);
    uint4 vb = *(const uint4*)(Vb + (size_t)sr * 4096 + kbase + sc + 32);
    *(uint4*)&K_lds[sr][sc]      = ka;
    *(uint4*)&K_lds[sr][sc + 32] = kb;
    *(uint4*)&V_lds[sr][sc]      = va;
    *(uint4*)&V_lds[sr][sc + 32] = vb;
  }
  __syncthreads();

  for (int kt = 0; kt < NKT; ++kt) {
    const bool pre = (kt + 1 < NKT);

    // issue next tile's global loads early (latency hides under MFMA+exp2)
    uint4 ka, kb, va, vb;
    if (pre) {
      const int k1 = kbase + (kt + 1) * 64;
      const u16* kg = Kb + (size_t)k1 * 64;
      ka = *(const uint4*)(kg + (size_t)sr * 64 + sc);
      kb = *(const uint4*)(kg + (size_t)sr * 64 + sc + 32);
      va = *(const uint4*)(Vb + (size_t)sr * 4096 + k1 + sc);
      vb = *(const uint4*)(Vb + (size_t)sr * 4096 + k1 + sc + 32);
    }

    // two 32-k phases over this 64-k tile
    #pragma unroll
    for (int kh = 0; kh < 2; ++kh) {
      short8 kf[2][2], vf[4];
      #pragma unroll
      for (int m = 0; m < 2; ++m) {
        kf[m][0] = *(const short8*)&K_lds[(kh * 2 + m) * 16 + l15][quad * 8];
        kf[m][1] = *(const short8*)&K_lds[(kh * 2 + m) * 16 + l15][quad * 8 + 32];
      }
      #pragma unroll
      for (int nd = 0; nd < 4; ++nd)
        vf[nd] = *(const short8*)&V_lds[nd * 16 + l15][kh * 32 + quad * 8];

      #pragma unroll
      for (int m = 0; m < 2; ++m) {
        #pragma unroll
        for (int nt = 0; nt < 2; ++nt) {
          f32x4 s = {0.f, 0.f, 0.f, 0.f};
          s = __builtin_amdgcn_mfma_f32_16x16x32_bf16(kf[m][0], qf[nt][0], s, 0, 0, 0);
          s = __builtin_amdgcn_mfma_f32_16x16x32_bf16(kf[m][1], qf[nt][1], s, 0, 0, 0);
          float p0 = exp2f(s[0]), p1 = exp2f(s[1]), p2 = exp2f(s[2]), p3 = exp2f(s[3]);
          lsum[nt] += (p0 + p1) + (p2 + p3);
          u32 u0 = __float_as_uint(p0) + 0x8000u;
          u32 u1 = __float_as_uint(p1) + 0x8000u;
          u32 u2 = __float_as_uint(p2) + 0x8000u;
          u32 u3 = __float_as_uint(p3) + 0x8000u;
          union { uint2 u; short4v s4; } pk;
          pk.u.x = __builtin_amdgcn_perm(u1, u0, 0x07060302u);
          pk.u.y = __builtin_amdgcn_perm(u3, u2, 0x07060302u);
          *(short4v*)(pw + (nt * 16 + l15) * 40 + m * 16 + quad * 4) = pk.s4;
        }
      }

      asm volatile("" ::: "memory");

      #pragma unroll
      for (int mq = 0; mq < 2; ++mq) {
        const short8 pa = *(const short8*)(pw + (mq * 16 + l15) * 40 + quad * 8);
        #pragma unroll
        for (int nd = 0; nd < 4; ++nd)
          oacc[mq][nd] = __builtin_amdgcn_mfma_f32_16x16x32_bf16(pa, vf[nd], oacc[mq][nd], 0, 0, 0);
      }

      asm volatile("" ::: "memory");   // P_lds reused next phase
    }

    __syncthreads();   // all waves done reading K/V buffers
    if (pre) {
      *(uint4*)&K_lds[sr][sc]      = ka;
      *(uint4*)&K_lds[sr][sc + 32] = kb;
      *(uint4*)&V_lds[sr][sc]      = va;
      *(uint4*)&V_lds[sr][sc + 32] = vb;
      __syncthreads();
    }
  }

  #pragma unroll
  for (int nt = 0; nt < 2; ++nt) {
    float v = lsum[nt];
    v += __shfl_xor(v, 16, 64);
    v += __shfl_xor(v, 32, 64);
    lsum[nt] = v;
  }
  float* LpB = Lp + ((size_t)ks * 4 + b) * 4096;
  if (quad == 0) {
    #pragma unroll
    for (int nt = 0; nt < 2; ++nt)
      LpB[q0 + nt * 16 + l15] = lsum[nt];
  }

  u16* Ob = Opart + ((size_t)ks * 4 + b) * 4096 * 64;
  #pragma unroll
  for (int mq = 0; mq < 2; ++mq)
    #pragma unroll
    for (int nd = 0; nd < 4; ++nd)
      #pragma unroll
      for (int r = 0; r < 4; ++r) {
        int q = q0 + mq * 16 + quad * 4 + r;
        Ob[(size_t)q * 64 + nd * 16 + l15] = f2b(oacc[mq][nd][r]);
      }
}

// grid (64 n-tiles of 64, 4 batches), block 256 = 4 waves.
// Phase 1: Y[n][64] = sum_ks(Opart)/sum_ks(Lp) -> LDS bf16. Phase 2: MFMA proj
// C[o][n] = mfma(A=W[o][ci], B=Y[n][ci]); out = C + Wb + x0.
__global__ __launch_bounds__(256) void out_fused_kernel(
    const u16* __restrict__ Opart, const float* __restrict__ Lp,
    const float* __restrict__ Wf, const float* __restrict__ Wbf,
    const float* __restrict__ x0, float* __restrict__ out)
{
  const int n0 = blockIdx.x * 64;
  const int b  = blockIdx.y;
  const int t  = threadIdx.x;

  __shared__ __align__(16) short Ys[64][72];   // [n][ci], +8 pad

  {
    const int nl = t >> 2;          // 0..63
    const int q4 = t & 3;           // 16-ch chunk
    const int ng = n0 + nl;

    float l = 0.f;
    #pragma unroll
    for (int ks = 0; ks < KSPLIT; ++ks)
      l += Lp[((size_t)ks * 4 + b) * 4096 + ng];

    float a[16];
    #pragma unroll
    for (int j = 0; j < 16; ++j) a[j] = 0.f;
    #pragma unroll
    for (int ks = 0; ks < KSPLIT; ++ks) {
      const uint4* row = (const uint4*)(Opart + (((size_t)ks * 4 + b) * 4096 + ng) * 64 + q4 * 16);
      #pragma unroll
      for (int v = 0; v < 2; ++v) {
        uint4 r = row[v];
        u32 wds[4] = {r.x, r.y, r.z, r.w};
        #pragma unroll
        for (int j = 0; j < 4; ++j) {
          a[v * 8 + 2 * j]     += __uint_as_float(wds[j] << 16);
          a[v * 8 + 2 * j + 1] += __uint_as_float(wds[j] & 0xffff0000u);
        }
      }
    }
    const float rinv = 1.f / l;
    union { u32 w[8]; short8 s8[2]; } pk;
    #pragma unroll
    for (int j = 0; j < 8; ++j)
      pk.w[j] = (u32)f2b(a[2 * j] * rinv) | ((u32)f2b(a[2 * j + 1] * rinv) << 16);
    *(short8*)&Ys[nl][q4 * 16]     = pk.s8[0];
    *(short8*)&Ys[nl][q4 * 16 + 8] = pk.s8[1];
  }
  asm volatile("" ::: "memory");
  __syncthreads();

  const int wave = t >> 6;
  const int lane = t & 63;
  const int quad = lane >> 4, l15 = lane & 15;

  f32x4 acc[2][4];   // [o-tile within wave][n-tile]
  #pragma unroll
  for (int i = 0; i < 2; ++i)
    #pragma unroll
    for (int j = 0; j < 4; ++j) acc[i][j] = (f32x4){0.f, 0.f, 0.f, 0.f};

  #pragma unroll
  for (int kk = 0; kk < 2; ++kk) {
    short8 wf[2], yf[4];
    #pragma unroll
    for (int ot = 0; ot < 2; ++ot)
      wf[ot] = load_w_frag(Wf + ((wave * 2 + ot) * 16 + l15) * 64 + kk * 32 + quad * 8, 1.f);
    #pragma unroll
    for (int nt = 0; nt < 4; ++nt)
      yf[nt] = *(const short8*)&Ys[nt * 16 + l15][kk * 32 + quad * 8];
    #pragma unroll
    for (int i = 0; i < 2; ++i)
      #pragma unroll
      for (int j = 0; j < 4; ++j)
        acc[i][j] = __builtin_amdgcn_mfma_f32_16x16x32_bf16(wf[i], yf[j], acc[i][j], 0, 0, 0);
  }

  #pragma unroll
  for (int ot = 0; ot < 2; ++ot)
    #pragma unroll
    for (int r = 0; r < 4; ++r) {
      const int o = (wave * 2 + ot) * 16 + quad * 4 + r;
      const float bv = Wbf[o];
      #pragma unroll
      for (int nt = 0; nt < 4; ++nt) {
        const size_t idx = ((size_t)(b * 128 + o)) * 4096 + n0 + nt * 16 + l15;
        out[idx] = acc[ot][nt][r] + bv + x0[idx];
      }
    }
}

extern "C" void kernel_launch(void* const* d_in, const int* in_sizes, int n_in,
                              void* d_out, int out_size, void* d_ws, size_t ws_size,
                              hipStream_t stream) {
  const float* x0 = (const float*)d_in[0];
  const float* x1 = (const float*)d_in[1];
  const float* gw = (const float*)d_in[2];
  const float* gb = (const float*)d_in[3];
  const float* tw = (const float*)d_in[4];
  const float* tb = (const float*)d_in[5];
  const float* pw = (const float*)d_in[6];
  const float* pb = (const float*)d_in[7];
  const float* Ww = (const float*)d_in[8];
  const float* Wb = (const float*)d_in[9];
  float* out = (float*)d_out;

  char* ws = (char*)d_ws;
  u16*   Qw    = (u16*)(ws + 0);
  u16*   Kw    = (u16*)(ws + (2u << 20));
  u16*   Vtw   = (u16*)(ws + (4u << 20));
  u16*   Opart = (u16*)(ws + (6u << 20));
  float* Lp    = (float*)(ws + (22u << 20));   // 22.5 MB total

  qkv_fused_kernel<<<dim3(64, 4), dim3(256), 0, stream>>>(
      x0, x1, tw, tb, pw, pb, gw, gb, Qw, Kw, Vtw);

  attn_kernel<<<dim3(32, 4, KSPLIT), dim3(256), 0, stream>>>(Qw, Kw, Vtw, Opart, Lp);

  out_fused_kernel<<<dim3(64, 4), dim3(256), 0, stream>>>(
      Opart, Lp, Ww, Wb, x0, out);
}